// Round 1
// baseline (816.652 us; speedup 1.0000x reference)
//
#include <hip/hip_runtime.h>
#include <math.h>

// Skip-gram negative-sampling loss.
//   loss_b = log_sigmoid(mean_d(u[up_b]*v[vp_b])) + log_sigmoid(-mean_n(dot_d(v[vn_bn], u[up_b])))
//   out    = -sum_b(loss_b) / B
// Memory-bound random gather: 12 rows x 512 B per batch element (~402 MB total).

__device__ __forceinline__ float log_sigmoid(float x) {
    // stable: min(x,0) - log1p(exp(-|x|))
    return fminf(x, 0.f) - log1pf(expf(-fabsf(x)));
}

constexpr int WAVES_PER_BLOCK = 4;   // block = 256 threads
constexpr int NBLOCKS = 2048;        // 2048*256 = 524288 threads = 32 waves/CU (full occupancy)

template <int NT>
__global__ __launch_bounds__(256) void sg_main(
    const float* __restrict__ u_w,
    const float* __restrict__ v_w,
    const int* __restrict__ u_pos,
    const int* __restrict__ v_pos,
    const int* __restrict__ v_neg,
    float* __restrict__ partial,
    int B, int N)
{
    const int lane = threadIdx.x & 63;
    const int wid  = threadIdx.x >> 6;
    const int wavesTotal = gridDim.x * WAVES_PER_BLOCK;

    float acc = 0.f;

    for (int b = blockIdx.x * WAVES_PER_BLOCK + wid; b < B; b += wavesTotal) {
        // --- gather indices first so all row loads can issue together ---
        const int iu = u_pos[b];
        const int iv = v_pos[b];
        const int nn = (NT > 0) ? NT : N;

        // one 512 B row per wave: lane i holds elements [2i, 2i+1]
        const float2 u = ((const float2*)(u_w + (size_t)iu * 128))[lane];
        const float2 v = ((const float2*)(v_w + (size_t)iv * 128))[lane];

        float pos = u.x * v.x + u.y * v.y;

        float neg = 0.f;
        const int* vn = v_neg + (size_t)b * nn;
        if (NT > 0) {
            int idx[NT > 0 ? NT : 1];
#pragma unroll
            for (int n = 0; n < NT; ++n) idx[n] = vn[n];
#pragma unroll
            for (int n = 0; n < NT; ++n) {
                const float2 w = ((const float2*)(v_w + (size_t)idx[n] * 128))[lane];
                neg += u.x * w.x + u.y * w.y;
            }
        } else {
            for (int n = 0; n < N; ++n) {
                const float2 w = ((const float2*)(v_w + (size_t)vn[n] * 128))[lane];
                neg += u.x * w.x + u.y * w.y;
            }
        }

        // two wave-wide butterfly reductions (pos, neg) — 6 steps each
#pragma unroll
        for (int off = 32; off; off >>= 1) {
            pos += __shfl_xor(pos, off);
            neg += __shfl_xor(neg, off);
        }

        const float score = pos * (1.f / 128.f);           // mean over D
        const float nsc   = neg / (float)((NT > 0) ? NT : N); // mean over N (dot is a sum over D)
        acc += log_sigmoid(score) + log_sigmoid(-nsc);
    }

    // per-block reduction (all lanes of a wave hold identical acc after butterfly)
    __shared__ float red[WAVES_PER_BLOCK];
    if (lane == 0) red[wid] = acc;
    __syncthreads();
    if (threadIdx.x == 0) {
        float s = 0.f;
#pragma unroll
        for (int i = 0; i < WAVES_PER_BLOCK; ++i) s += red[i];
        partial[blockIdx.x] = s;
    }
}

__global__ __launch_bounds__(256) void sg_reduce(
    const float* __restrict__ partial, int nPartial,
    float* __restrict__ out, float invB)
{
    float s = 0.f;
    for (int i = threadIdx.x; i < nPartial; i += 256) s += partial[i];
#pragma unroll
    for (int off = 32; off; off >>= 1) s += __shfl_xor(s, off);
    __shared__ float red[4];
    const int lane = threadIdx.x & 63;
    const int wid  = threadIdx.x >> 6;
    if (lane == 0) red[wid] = s;
    __syncthreads();
    if (threadIdx.x == 0) {
        out[0] = -(red[0] + red[1] + red[2] + red[3]) * invB;
    }
}

extern "C" void kernel_launch(void* const* d_in, const int* in_sizes, int n_in,
                              void* d_out, int out_size, void* d_ws, size_t ws_size,
                              hipStream_t stream) {
    const float* u_w   = (const float*)d_in[0];
    const float* v_w   = (const float*)d_in[1];
    const int*   u_pos = (const int*)d_in[2];
    const int*   v_pos = (const int*)d_in[3];
    const int*   v_neg = (const int*)d_in[4];
    const int B = in_sizes[2];
    const int N = in_sizes[4] / B;

    float* partial = (float*)d_ws;   // NBLOCKS floats (8 KB) of scratch

    if (N == 10) {
        sg_main<10><<<NBLOCKS, 256, 0, stream>>>(u_w, v_w, u_pos, v_pos, v_neg, partial, B, N);
    } else {
        sg_main<0><<<NBLOCKS, 256, 0, stream>>>(u_w, v_w, u_pos, v_pos, v_neg, partial, B, N);
    }
    sg_reduce<<<1, 256, 0, stream>>>(partial, NBLOCKS, (float*)d_out, 1.f / (float)B);
}